// Round 1
// 187.190 us; speedup vs baseline: 1.0483x; 1.0483x over previous
//
#include <hip/hip_runtime.h>

// ---- problem constants (B,H0,W0,C)=(16,56,56,96), NH=3, WS=7, SS=3, HID=384, NCL=128 ----
#define NB 16
#define NHH 56
#define NWW 56
#define NC 96
#define NL (NHH*NWW)          // 3136
#define NTOK (NB*NL)          // 50176
#define WSZ 7
#define NT 49                 // tokens per window
#define SSH 3
#define NWIN 1024             // 16 * 8 * 8
#define HDIM 32
#define HID_ 384
#define NCL_ 128
#define NLIT 768
#define EPS_ 1e-6f
#define LOG_EPS -13.815510558f

typedef unsigned short u16;
typedef unsigned int   u32;
typedef __attribute__((ext_vector_type(8))) short short8;   // 8 bf16 (4 VGPRs)
typedef __attribute__((ext_vector_type(4))) float f32x4;    // MFMA C/D

__device__ __forceinline__ float us2f(u16 u) {
  union { u32 u; float f; } x; x.u = ((u32)u) << 16; return x.f;
}
__device__ __forceinline__ u16 f2us(float f) {   // RNE float->bf16
  union { float f; u32 u; } x; x.f = f;
  u32 lsb = (x.u >> 16) & 1u;
  return (u16)((x.u + 0x7fffu + lsb) >> 16);
}
__device__ __forceinline__ float sigmoidf_(float x) { return 1.f / (1.f + __expf(-x)); }

// ---------------- K0: build bf16 constants ----------------
// maskb is stored COLUMN-INTERLEAVED: permuted col q holds source literal
// j = (q&1) ? 384 + q/2 : q/2.  k4 writes lit[] in the same interleaved
// order (literal o and literal 384+o are adjacent -> one u32 LDS write).
__global__ __launch_bounds__(256) void k0_prep(const float* __restrict__ tm_inc,
                                               const float* __restrict__ pin_w,
                                               const float* __restrict__ tm_out,
                                               const float* __restrict__ qkv_w,
                                               const float* __restrict__ proj_w,
                                               u16* __restrict__ maskb,
                                               u16* __restrict__ pinwb,
                                               u16* __restrict__ tmoT,
                                               u16* __restrict__ qkvwb,
                                               u16* __restrict__ projwb) {
  int idx = blockIdx.x * 256 + threadIdx.x;
  if (idx < NCL_ * NLIT) {
    int c = idx / NLIT, q = idx - c * NLIT;
    int j = (q & 1) ? (q >> 1) + HID_ : (q >> 1);
    maskb[idx] = (tm_inc[(size_t)c * NLIT + j] > 0.f) ? (u16)0x3F80 : (u16)0;
  }
  if (idx < HID_ * NC)
    pinwb[idx] = f2us(pin_w[idx]);
  if (idx < NC * NCL_) {
    int c = idx / NCL_, k = idx - c * NCL_;
    tmoT[idx] = f2us(tm_out[(size_t)k * NC + c]);
  }
  if (idx < 3 * NC * NC)
    qkvwb[idx] = f2us(qkv_w[idx]);
  if (idx < NC * NC)
    projwb[idx] = f2us(proj_w[idx]);
}

// ---------------- K2: LN1 + window gather + MFMA attention + proj + residual scatter ----------------
// One block = one window. 4 waves; wave w owns query rows 16w..16w+15.
// syb triple-duty: LN1'd y -> q (QKV phase, wave-own rows) -> attn-out (PV, wave-own rows).
// NO barrier after LN: wave w's A-frag rows are written by wave w's own LN threads.
// LDS: syb 13,312 + sk 13,312 + svT 13,824 = 40,448 B -> 4 blocks/CU = whole 1024-block grid resident.
// sp (softmax P staging) ALIASES sk: all sk reads happen in the all-head score
// phase, which is fenced from the sp writes by barrier B3s.
__global__ __launch_bounds__(256, 4) void k2_attn(const float* __restrict__ x,
                                               const float* __restrict__ n1g,
                                               const float* __restrict__ n1b,
                                               const u16* __restrict__ qkvwb,
                                               const float* __restrict__ qkv_b,
                                               const u16* __restrict__ projwb,
                                               const float* __restrict__ proj_b,
                                               float* __restrict__ x1) {
  __shared__ __align__(16) u16 syb[64 * 104];
  __shared__ __align__(16) u16 sk [64 * 104];
  __shared__ __align__(16) u16 svT[96 * 72];
  const int tid  = threadIdx.x;
  const int wave = tid >> 6;
  const int lane = tid & 63;
  const int l16  = lane & 15;
  const int quad = lane >> 4;
  const int win  = blockIdx.x;
  const int t0   = wave * 16;
  const int bb = win >> 6, wl = win & 63;
  const int hbase = (wl >> 3) * WSZ, wbase = (wl & 7) * WSZ;

  // ---- LN1 head: 4 threads per token; gather from x with inverse global roll ----
  {
    const int t = tid >> 2, s = tid & 3;
    if (t < NT) {
      int hp = hbase + t / WSZ, wp = wbase + t % WSZ;
      int h = hp + SSH; if (h >= NHH) h -= NHH;
      int w = wp + SSH; if (w >= NWW) w -= NWW;
      const float* xp = x + ((size_t)bb * NL + (size_t)h * NWW + w) * NC;
      float4 v[6];
      float sum = 0.f;
      #pragma unroll
      for (int k = 0; k < 6; ++k) {
        v[k] = *reinterpret_cast<const float4*>(xp + s * 4 + k * 16);
        sum += v[k].x + v[k].y + v[k].z + v[k].w;
      }
      sum += __shfl_xor(sum, 1); sum += __shfl_xor(sum, 2);
      float mean = sum * (1.f / 96.f);
      float ssq = 0.f;
      #pragma unroll
      for (int k = 0; k < 6; ++k) {
        float d0 = v[k].x - mean, d1 = v[k].y - mean;
        float d2 = v[k].z - mean, d3 = v[k].w - mean;
        ssq += d0 * d0 + d1 * d1 + d2 * d2 + d3 * d3;
      }
      ssq += __shfl_xor(ssq, 1); ssq += __shfl_xor(ssq, 2);
      float rstd = rsqrtf(ssq * (1.f / 96.f) + 1e-5f);
      #pragma unroll
      for (int k = 0; k < 6; ++k) {
        int c = s * 4 + k * 16;
        const float4 g4 = *reinterpret_cast<const float4*>(n1g + c);
        const float4 b4 = *reinterpret_cast<const float4*>(n1b + c);
        syb[t * 104 + c + 0] = f2us((v[k].x - mean) * rstd * g4.x + b4.x);
        syb[t * 104 + c + 1] = f2us((v[k].y - mean) * rstd * g4.y + b4.y);
        syb[t * 104 + c + 2] = f2us((v[k].z - mean) * rstd * g4.z + b4.z);
        syb[t * 104 + c + 3] = f2us((v[k].w - mean) * rstd * g4.w + b4.w);
      }
    } else {
      #pragma unroll
      for (int k = 0; k < 6; ++k) {
        int c = s * 4 + k * 16;
        syb[t * 104 + c + 0] = 0; syb[t * 104 + c + 1] = 0;
        syb[t * 104 + c + 2] = 0; syb[t * 104 + c + 3] = 0;
      }
    }
  }
  // NO __syncthreads() here: A-frag rows below are wave-own (see header comment).

  // ---- QKV: M=64, N=288 (18 tiles), K=96 (3 steps); depth-4 B-frag ring. ----
  {
    short8 afr[3];
    #pragma unroll
    for (int ks = 0; ks < 3; ++ks)
      afr[ks] = *reinterpret_cast<const short8*>(&syb[(t0 + l16) * 104 + quad * 8 + ks * 32]);
    short8 rb[4][3];
    #pragma unroll
    for (int p = 0; p < 4; ++p)
      #pragma unroll
      for (int ks = 0; ks < 3; ++ks)
        rb[p][ks] = *reinterpret_cast<const short8*>(
            qkvwb + (size_t)(p * 16 + l16) * NC + quad * 8 + ks * 32);
    #pragma unroll
    for (int nt = 0; nt < 18; ++nt) {
      const int n0 = nt * 16;
      const float bias = qkv_b[n0 + l16];
      short8 b0 = rb[nt & 3][0], b1 = rb[nt & 3][1], b2 = rb[nt & 3][2];
      if (nt + 4 < 18) {
        #pragma unroll
        for (int ks = 0; ks < 3; ++ks)
          rb[nt & 3][ks] = *reinterpret_cast<const short8*>(
              qkvwb + (size_t)((nt + 4) * 16 + l16) * NC + quad * 8 + ks * 32);
      }
      f32x4 acc = {0.f, 0.f, 0.f, 0.f};
      acc = __builtin_amdgcn_mfma_f32_16x16x32_bf16(afr[0], b0, acc, 0, 0, 0);
      acc = __builtin_amdgcn_mfma_f32_16x16x32_bf16(afr[1], b1, acc, 0, 0, 0);
      acc = __builtin_amdgcn_mfma_f32_16x16x32_bf16(afr[2], b2, acc, 0, 0, 0);
      const int part = nt / 6;                 // 0=q 1=k 2=v
      const int oc = n0 - part * 96 + l16;
      if (part < 2) {
        u16* dst = (part == 0) ? syb : sk;     // q overwrites y in wave-own rows
        #pragma unroll
        for (int r = 0; r < 4; ++r)
          dst[(t0 + quad * 4 + r) * 104 + oc] = f2us(acc[r] + bias);
      } else {
        #pragma unroll
        for (int r = 0; r < 4; ++r)
          svT[oc * 72 + (t0 + quad * 4 + r)] = f2us(acc[r] + bias);
      }
    }
  }
  __syncthreads();   // B2: k/v (cross-wave) must be complete

  // ---- all-head scores first (12 independent MFMAs, max MLP), then per-head softmax+PV ----
  u16* spw = sk + wave * 16 * 72;              // sp ALIASES sk (sk dead after score phase)
  const float sscale = 0.17677669529663687f;
  short8 qf[3];
  f32x4 s[3][4];
  #pragma unroll
  for (int h = 0; h < 3; ++h)
    qf[h] = *reinterpret_cast<const short8*>(&syb[(t0 + l16) * 104 + h * HDIM + quad * 8]);
  #pragma unroll
  for (int h = 0; h < 3; ++h) {
    const int d0 = h * HDIM;
    #pragma unroll
    for (int nt = 0; nt < 4; ++nt) {
      short8 kf = *reinterpret_cast<const short8*>(&sk[(nt * 16 + l16) * 104 + d0 + quad * 8]);
      f32x4 a = {0.f, 0.f, 0.f, 0.f};
      s[h][nt] = __builtin_amdgcn_mfma_f32_16x16x32_bf16(qf[h], kf, a, 0, 0, 0);
    }
  }
  __syncthreads();   // B3s: all sk reads complete before spw (sk-alias) writes
  #pragma unroll
  for (int h = 0; h < 3; ++h) {
    const int d0 = h * HDIM;
    #pragma unroll
    for (int nt = 0; nt < 4; ++nt)
      #pragma unroll
      for (int r = 0; r < 4; ++r) s[h][nt][r] *= sscale;
    if (l16 >= 1) {                       // key col 48+l16 >= 49 -> mask
      #pragma unroll
      for (int r = 0; r < 4; ++r) s[h][3][r] = -1e30f;
    }
    #pragma unroll
    for (int r = 0; r < 4; ++r) {
      float m = fmaxf(fmaxf(s[h][0][r], s[h][1][r]), fmaxf(s[h][2][r], s[h][3][r]));
      #pragma unroll
      for (int off = 8; off > 0; off >>= 1) m = fmaxf(m, __shfl_xor(m, off, 16));
      float e0 = __expf(s[h][0][r] - m), e1 = __expf(s[h][1][r] - m);
      float e2 = __expf(s[h][2][r] - m), e3 = __expf(s[h][3][r] - m);
      float sum = e0 + e1 + e2 + e3;
      #pragma unroll
      for (int off = 8; off > 0; off >>= 1) sum += __shfl_xor(sum, off, 16);
      float inv = 1.f / sum;
      const int row = quad * 4 + r;
      spw[row * 72 +      l16] = f2us(e0 * inv);
      spw[row * 72 + 16 + l16] = f2us(e1 * inv);
      spw[row * 72 + 32 + l16] = f2us(e2 * inv);
      spw[row * 72 + 48 + l16] = f2us(e3 * inv);
    }
    short8 pa[2];
    pa[0] = *reinterpret_cast<const short8*>(&spw[l16 * 72 + quad * 8]);
    pa[1] = *reinterpret_cast<const short8*>(&spw[l16 * 72 + 32 + quad * 8]);
    #pragma unroll
    for (int nt = 0; nt < 2; ++nt) {
      const int c0 = d0 + nt * 16;
      f32x4 acc = {0.f, 0.f, 0.f, 0.f};
      #pragma unroll
      for (int ks = 0; ks < 2; ++ks) {
        short8 vb = *reinterpret_cast<const short8*>(&svT[(c0 + l16) * 72 + ks * 32 + quad * 8]);
        acc = __builtin_amdgcn_mfma_f32_16x16x32_bf16(pa[ks], vb, acc, 0, 0, 0);
      }
      #pragma unroll
      for (int r = 0; r < 4; ++r)
        syb[(t0 + quad * 4 + r) * 104 + c0 + l16] = f2us(acc[r]);
    }
  }

  // ---- proj: N=96 (6 tiles), K=96 (3 steps); prefetched residuals + depth-2 B ring ----
  {
    short8 aa[3];
    #pragma unroll
    for (int ks = 0; ks < 3; ++ks)
      aa[ks] = *reinterpret_cast<const short8*>(&syb[(t0 + l16) * 104 + quad * 8 + ks * 32]);

    size_t tokr[4]; bool tval[4];
    #pragma unroll
    for (int r = 0; r < 4; ++r) {
      const int t = t0 + quad * 4 + r;
      tval[r] = (t < NT);
      int rr = t / WSZ + SSH; if (rr >= WSZ) rr -= WSZ;
      int qq = t % WSZ + SSH; if (qq >= WSZ) qq -= WSZ;
      tokr[r] = (size_t)bb * NL + (size_t)(hbase + rr) * NWW + (wbase + qq);
    }
    float xv[6][4];
    #pragma unroll
    for (int nt = 0; nt < 6; ++nt)
      #pragma unroll
      for (int r = 0; r < 4; ++r)
        xv[nt][r] = tval[r] ? x[tokr[r] * NC + nt * 16 + l16] : 0.f;

    short8 pbr[2][3];
    #pragma unroll
    for (int ks = 0; ks < 3; ++ks)
      pbr[0][ks] = *reinterpret_cast<const short8*>(
          projwb + (size_t)l16 * NC + quad * 8 + ks * 32);
    #pragma unroll
    for (int nt = 0; nt < 6; ++nt) {
      const int n0 = nt * 16;
      const float pb = proj_b[n0 + l16];
      short8 b0 = pbr[nt & 1][0], b1 = pbr[nt & 1][1], b2 = pbr[nt & 1][2];
      if (nt + 1 < 6) {
        #pragma unroll
        for (int ks = 0; ks < 3; ++ks)
          pbr[(nt + 1) & 1][ks] = *reinterpret_cast<const short8*>(
              projwb + (size_t)((nt + 1) * 16 + l16) * NC + quad * 8 + ks * 32);
      }
      f32x4 acc = {0.f, 0.f, 0.f, 0.f};
      acc = __builtin_amdgcn_mfma_f32_16x16x32_bf16(aa[0], b0, acc, 0, 0, 0);
      acc = __builtin_amdgcn_mfma_f32_16x16x32_bf16(aa[1], b1, acc, 0, 0, 0);
      acc = __builtin_amdgcn_mfma_f32_16x16x32_bf16(aa[2], b2, acc, 0, 0, 0);
      #pragma unroll
      for (int r = 0; r < 4; ++r) {
        if (tval[r])
          x1[tokr[r] * NC + n0 + l16] = xv[nt][r] + acc[r] + pb;
      }
    }
  }
}

// ---------------- K4: double-LN + TM-FFN via MFMA; 32 tokens/block, 8 waves (512 thr) ----------------
// LDS = ONE buffer lit[32*776] = 49,664 B -> 3 blocks/CU (was 58,368 -> 2).
// szb (LN output, 32x104) and claT (clause^T, 32x136) ALIAS lit; disjoint
// lifetimes fenced by barriers B1b (a_pin reads done) and B2b (lit reads done).
// lit columns are INTERLEAVED (literal o at col 2o, literal 384+o at col 2o+1,
// matching k0's maskb permutation) so each lane stores one aligned u32 pair:
// halves the lit ds_write count and makes the bank pattern 2-way (free).
__global__ __launch_bounds__(512, 6) void k4_ffn(const float* __restrict__ x1,
                                              const float* __restrict__ g2,
                                              const float* __restrict__ b2,
                                              const float* __restrict__ gf,
                                              const float* __restrict__ bf,
                                              const u16* __restrict__ pinwb,
                                              const float* __restrict__ pin_b,
                                              const u16* __restrict__ maskb,
                                              const u16* __restrict__ tmoT,
                                              const float* __restrict__ gate,
                                              float* __restrict__ out) {
  __shared__ __align__(16) u16 lit[32 * 776];   // bf16 log-literals [t][perm(j)]
  u16* szb  = lit;                              // alias: dies at B1b
  u16* claT = lit;                              // alias: born after B2b
  const int tid  = threadIdx.x;
  const int wave = tid >> 6;
  const int lane = tid & 63;
  const int l16  = lane & 15;
  const int quad = lane >> 4;
  const size_t tok0 = (size_t)blockIdx.x * 32;

  // ---- LN(LN(x1)) head: 16 lanes per token, 6 channels each (float2 x 3) ----
  {
    const int t = tid >> 4, s = tid & 15;
    const float* xp = x1 + (tok0 + t) * NC;
    float2 v[3];
    float sum = 0.f;
    #pragma unroll
    for (int k = 0; k < 3; ++k) {
      const int c = s * 2 + k * 32;
      v[k] = *reinterpret_cast<const float2*>(xp + c);
      sum += v[k].x + v[k].y;
    }
    #pragma unroll
    for (int off = 8; off > 0; off >>= 1) sum += __shfl_xor(sum, off, 16);
    const float mean = sum * (1.f / 96.f);
    float ssq = 0.f;
    #pragma unroll
    for (int k = 0; k < 3; ++k) {
      float d0 = v[k].x - mean, d1 = v[k].y - mean;
      ssq += d0 * d0 + d1 * d1;
    }
    #pragma unroll
    for (int off = 8; off > 0; off >>= 1) ssq += __shfl_xor(ssq, off, 16);
    const float rstd = rsqrtf(ssq * (1.f / 96.f) + 1e-5f);
    float tv[6];
    float sum2 = 0.f;
    #pragma unroll
    for (int k = 0; k < 3; ++k) {
      const int c = s * 2 + k * 32;
      const float2 gg = *reinterpret_cast<const float2*>(g2 + c);
      const float2 bb = *reinterpret_cast<const float2*>(b2 + c);
      tv[2 * k]     = (v[k].x - mean) * rstd * gg.x + bb.x;
      tv[2 * k + 1] = (v[k].y - mean) * rstd * gg.y + bb.y;
      sum2 += tv[2 * k] + tv[2 * k + 1];
    }
    #pragma unroll
    for (int off = 8; off > 0; off >>= 1) sum2 += __shfl_xor(sum2, off, 16);
    const float mean2 = sum2 * (1.f / 96.f);
    float ssq2 = 0.f;
    #pragma unroll
    for (int k = 0; k < 3; ++k) {
      float d0 = tv[2 * k] - mean2, d1 = tv[2 * k + 1] - mean2;
      ssq2 += d0 * d0 + d1 * d1;
    }
    #pragma unroll
    for (int off = 8; off > 0; off >>= 1) ssq2 += __shfl_xor(ssq2, off, 16);
    const float rstd2 = rsqrtf(ssq2 * (1.f / 96.f) + 1e-5f);
    #pragma unroll
    for (int k = 0; k < 3; ++k) {
      const int c = s * 2 + k * 32;
      const float2 gg = *reinterpret_cast<const float2*>(gf + c);
      const float2 bb = *reinterpret_cast<const float2*>(bf + c);
      u16 lo = f2us((tv[2 * k]     - mean2) * rstd2 * gg.x + bb.x);
      u16 hi = f2us((tv[2 * k + 1] - mean2) * rstd2 * gg.y + bb.y);
      *reinterpret_cast<u32*>(&szb[t * 104 + c]) = (u32)lo | ((u32)hi << 16);
    }
  }
  __syncthreads();   // B1: szb complete

  const float gv = sigmoidf_(gate[0]);

  // A-frags for both pin M-tiles
  short8 a_pin[2][3];
  #pragma unroll
  for (int mt = 0; mt < 2; ++mt)
    #pragma unroll
    for (int ks = 0; ks < 3; ++ks)
      a_pin[mt][ks] = *reinterpret_cast<const short8*>(
          &szb[(mt * 16 + l16) * 104 + quad * 8 + ks * 32]);
  __syncthreads();   // B1b: all szb reads complete before lit (alias) writes

  // ---- pin gemm: wave w -> N-tiles [3w,3w+3); ALL 9 B-frags loaded up front; 2 MFMA per B-frag;
  //      softplus literals: log(sig(a)) = a - sp, log(1-sig(a)) = -sp;
  //      stored interleaved at cols (2o, 2o+1) as one u32 ----
  {
    float pbias[3];
    #pragma unroll
    for (int i = 0; i < 3; ++i) pbias[i] = pin_b[(wave * 3 + i) * 16 + l16];
    short8 pb[3][3];
    #pragma unroll
    for (int i = 0; i < 3; ++i)
      #pragma unroll
      for (int ks = 0; ks < 3; ++ks)
        pb[i][ks] = *reinterpret_cast<const short8*>(
            pinwb + (size_t)((wave * 3 + i) * 16 + l16) * NC + quad * 8 + ks * 32);
    #pragma unroll
    for (int i = 0; i < 3; ++i) {
      f32x4 acc0 = {0.f, 0.f, 0.f, 0.f}, acc1 = {0.f, 0.f, 0.f, 0.f};
      acc0 = __builtin_amdgcn_mfma_f32_16x16x32_bf16(a_pin[0][0], pb[i][0], acc0, 0, 0, 0);
      acc1 = __builtin_amdgcn_mfma_f32_16x16x32_bf16(a_pin[1][0], pb[i][0], acc1, 0, 0, 0);
      acc0 = __builtin_amdgcn_mfma_f32_16x16x32_bf16(a_pin[0][1], pb[i][1], acc0, 0, 0, 0);
      acc1 = __builtin_amdgcn_mfma_f32_16x16x32_bf16(a_pin[1][1], pb[i][1], acc1, 0, 0, 0);
      acc0 = __builtin_amdgcn_mfma_f32_16x16x32_bf16(a_pin[0][2], pb[i][2], acc0, 0, 0, 0);
      acc1 = __builtin_amdgcn_mfma_f32_16x16x32_bf16(a_pin[1][2], pb[i][2], acc1, 0, 0, 0);
      const int o = (wave * 3 + i) * 16 + l16;      // hidden unit in [0,384)
      const float pbv = pbias[i];
      #pragma unroll
      for (int r = 0; r < 4; ++r) {
        const float a0 = acc0[r] + pbv;
        const float sp0 = fmaxf(a0, 0.f) + __logf(1.f + __expf(-fabsf(a0)));
        const float a1 = acc1[r] + pbv;
        const float sp1 = fmaxf(a1, 0.f) + __logf(1.f + __expf(-fabsf(a1)));
        const int ta = quad * 4 + r, tb = 16 + quad * 4 + r;
        const u16 lo0 = f2us(fmaxf(a0 - sp0, LOG_EPS));
        const u16 hi0 = f2us(fmaxf(-sp0, LOG_EPS));
        const u16 lo1 = f2us(fmaxf(a1 - sp1, LOG_EPS));
        const u16 hi1 = f2us(fmaxf(-sp1, LOG_EPS));
        *reinterpret_cast<u32*>(&lit[ta * 776 + 2 * o]) = (u32)lo0 | ((u32)hi0 << 16);
        *reinterpret_cast<u32*>(&lit[tb * 776 + 2 * o]) = (u32)lo1 | ((u32)hi1 << 16);
      }
    }
  }
  __syncthreads();   // B2: lit complete

  // prefetch epilogue residuals (hidden behind the clause gemm)
  float xr[2][4];
  if (wave < 6) {
    const int c = wave * 16 + l16;
    #pragma unroll
    for (int r = 0; r < 4; ++r) {
      xr[0][r] = x1[(tok0 + quad * 4 + r) * NC + c];
      xr[1][r] = x1[(tok0 + 16 + quad * 4 + r) * NC + c];
    }
  }

  // ---- clause gemm: wave w -> clause tile w; depth-8 B ring; 2 MFMA per B-frag ----
  {
    const int ct = wave;
    const u16* bp0 = maskb + (size_t)(ct * 16 + l16) * NLIT + quad * 8;
    short8 rb0[8];
    #pragma unroll
    for (int p = 0; p < 8; ++p)
      rb0[p] = *reinterpret_cast<const short8*>(bp0 + p * 32);
    f32x4 c00 = {0.f, 0.f, 0.f, 0.f}, c10 = {0.f, 0.f, 0.f, 0.f};
    #pragma unroll
    for (int ks = 0; ks < 24; ++ks) {
      const int k0 = ks * 32 + quad * 8;
      short8 a0 = *reinterpret_cast<const short8*>(&lit[l16 * 776 + k0]);
      short8 a1 = *reinterpret_cast<const short8*>(&lit[(16 + l16) * 776 + k0]);
      short8 b0 = rb0[ks & 7];
      if (ks + 8 < 24)
        rb0[ks & 7] = *reinterpret_cast<const short8*>(bp0 + (ks + 8) * 32);
      c00 = __builtin_amdgcn_mfma_f32_16x16x32_bf16(a0, b0, c00, 0, 0, 0);
      c10 = __builtin_amdgcn_mfma_f32_16x16x32_bf16(a1, b0, c10, 0, 0, 0);
    }
    float e0[4], e1[4];
    #pragma unroll
    for (int r = 0; r < 4; ++r) { e0[r] = __expf(c00[r]); e1[r] = __expf(c10[r]); }
    __syncthreads();   // B2b: all lit reads complete before claT (alias) writes
    #pragma unroll
    for (int r = 0; r < 4; ++r) {
      const int ta = quad * 4 + r, tb = 16 + quad * 4 + r;
      claT[ta * 136 + ct * 16 + l16] = f2us(e0[r]);
      claT[tb * 136 + ct * 16 + l16] = f2us(e1[r]);
    }
  }
  __syncthreads();   // B3: claT complete

  // ---- logits = cla @ tm_out; 6 N-tiles over waves 0-5; fused blend epilogue ----
  if (wave < 6) {
    const int nt = wave;
    short8 btm[4];
    #pragma unroll
    for (int ks = 0; ks < 4; ++ks)
      btm[ks] = *reinterpret_cast<const short8*>(
          tmoT + (size_t)(nt * 16 + l16) * NCL_ + ks * 32 + quad * 8);
    f32x4 acc0 = {0.f, 0.f, 0.f, 0.f}, acc1 = {0.f, 0.f, 0.f, 0.f};
    #pragma unroll
    for (int ks = 0; ks < 4; ++ks) {
      const int k0 = ks * 32 + quad * 8;
      short8 a0 = *reinterpret_cast<const short8*>(&claT[l16 * 136 + k0]);
      short8 a1 = *reinterpret_cast<const short8*>(&claT[(16 + l16) * 136 + k0]);
      acc0 = __builtin_amdgcn_mfma_f32_16x16x32_bf16(a0, btm[ks], acc0, 0, 0, 0);
      acc1 = __builtin_amdgcn_mfma_f32_16x16x32_bf16(a1, btm[ks], acc1, 0, 0, 0);
    }
    const int c = nt * 16 + l16;
    #pragma unroll
    for (int r = 0; r < 4; ++r) {
      const int ta = quad * 4 + r, tb = 16 + quad * 4 + r;
      float lg0 = acc0[r], lg1 = acc1[r];
      out[(tok0 + ta) * NC + c] = xr[0][r] + gv * lg0 + (1.f - gv) * sigmoidf_(lg0);
      out[(tok0 + tb) * NC + c] = xr[1][r] + gv * lg1 + (1.f - gv) * sigmoidf_(lg1);
    }
  }
}

extern "C" void kernel_launch(void* const* d_in, const int* in_sizes, int n_in,
                              void* d_out, int out_size, void* d_ws, size_t ws_size,
                              hipStream_t stream) {
  (void)in_sizes; (void)n_in; (void)out_size; (void)ws_size;
  const float* x      = (const float*)d_in[0];
  const float* n1g    = (const float*)d_in[1];
  const float* n1b    = (const float*)d_in[2];
  const float* qkv_w  = (const float*)d_in[3];
  const float* qkv_b  = (const float*)d_in[4];
  const float* proj_w = (const float*)d_in[5];
  const float* proj_b = (const float*)d_in[6];
  const float* n2g    = (const float*)d_in[7];
  const float* n2b    = (const float*)d_in[8];
  const float* fng    = (const float*)d_in[9];
  const float* fnb    = (const float*)d_in[10];
  const float* pin_w  = (const float*)d_in[11];
  const float* pin_b  = (const float*)d_in[12];
  const float* tm_inc = (const float*)d_in[13];
  const float* tm_out = (const float*)d_in[14];
  const float* gate   = (const float*)d_in[15];

  float* x1 = (float*)d_ws;                         // NTOK*96 f32
  u16* maskb = (u16*)(x1 + (size_t)NTOK * NC);      // 128*768 bf16 (col-interleaved)
  u16* pinwb = maskb + NCL_ * NLIT;                 // 384*96 bf16
  u16* tmoT  = pinwb + HID_ * NC;                   // 96*128 bf16
  u16* qkvwb = tmoT + NC * NCL_;                    // 288*96 bf16
  u16* projwb= qkvwb + 3 * NC * NC;                 // 96*96 bf16

  hipLaunchKernelGGL(k0_prep, dim3(384), dim3(256), 0, stream,
                     tm_inc, pin_w, tm_out, qkv_w, proj_w, maskb, pinwb, tmoT, qkvwb, projwb);
  hipLaunchKernelGGL(k2_attn, dim3(NWIN), dim3(256), 0, stream,
                     x, n1g, n1b, qkvwb, qkv_b, projwb, proj_b, x1);
  hipLaunchKernelGGL(k4_ffn, dim3(NTOK / 32), dim3(512), 0, stream,
                     x1, n2g, n2b, fng, fnb, pinwb, pin_b, maskb, tmoT, gate, (float*)d_out);
}